// Round 1
// baseline (568.857 us; speedup 1.0000x reference)
//
#include <hip/hip_runtime.h>
#include <hip/hip_bf16.h>

#define NN 20000
#define CC 128

// ---------- math helpers ----------
__device__ __forceinline__ float fsigm(float x) {
    float e = __expf(-x);
    return __builtin_amdgcn_rcpf(1.0f + e);
}
__device__ __forceinline__ float fsoftplus(float x) {
    // log1p(exp(x)), stable: max(x,0) + log(1 + exp(-|x|))
    float a = fabsf(x);
    float t = __logf(1.0f + __expf(-a));
    return fmaxf(x, 0.0f) + t;
}

// ---------- encoder layer 1: (N x 32) @ (32 x 128) + b, relu ----------
__global__ __launch_bounds__(128) void enc1_kernel(
    const float* __restrict__ xp, const float* __restrict__ W,
    const float* __restrict__ b, float* __restrict__ Y) {
    __shared__ float xs[32];
    int row = blockIdx.x;
    int t = threadIdx.x;
    if (t < 32) xs[t] = xp[(long)row * 32 + t];
    __syncthreads();
    float acc = b[t];
#pragma unroll
    for (int k = 0; k < 32; ++k) acc += xs[k] * W[k * 128 + t];
    Y[(long)row * 128 + t] = fmaxf(acc, 0.0f);
}

// ---------- encoder layer 2: (N x 128) @ (128 x 128) + b (no relu) ----------
__global__ __launch_bounds__(256) void gemm_nc128_kernel(
    const float* __restrict__ X, const float* __restrict__ W,
    const float* __restrict__ b, float* __restrict__ Y) {
    __shared__ float xs[128 * 36];  // transposed tile xs[k*36 + r], padded
    int t = threadIdx.x;
    int m0 = blockIdx.x * 32;
#pragma unroll
    for (int i = 0; i < 16; ++i) {
        int id = t + 256 * i;
        int r = id >> 7, k = id & 127;
        xs[k * 36 + r] = X[(long)(m0 + r) * 128 + k];
    }
    __syncthreads();
    int cc = t & 127;
    int r0 = (t >> 7) * 16;
    float acc[16];
#pragma unroll
    for (int r = 0; r < 16; ++r) acc[r] = 0.0f;
    const float* pW = W + cc;
    for (int k = 0; k < 128; ++k) {
        float w = pW[k * 128];
        const float4* xr = (const float4*)&xs[k * 36 + r0];
#pragma unroll
        for (int j = 0; j < 4; ++j) {
            float4 xa = xr[j];
            acc[4 * j + 0] += xa.x * w;
            acc[4 * j + 1] += xa.y * w;
            acc[4 * j + 2] += xa.z * w;
            acc[4 * j + 3] += xa.w * w;
        }
    }
    float bb = b[cc];
#pragma unroll
    for (int r = 0; r < 16; ++r)
        Y[(long)(m0 + r0 + r) * 128 + cc] = acc[r] + bb;
}

// ---------- layer projection: H = x @ [Wf_top|Wf_bot|Ws_top|Ws_bot] (+bf,+bs on dst halves) ----------
__global__ __launch_bounds__(256) void proj512_kernel(
    const float* __restrict__ X, const float* __restrict__ Wf,
    const float* __restrict__ Wsp, const float* __restrict__ bf,
    const float* __restrict__ bs, float* __restrict__ H) {
    __shared__ float xs[128 * 36];
    int t = threadIdx.x;
    int m0 = blockIdx.x * 32;
#pragma unroll
    for (int i = 0; i < 16; ++i) {
        int id = t + 256 * i;
        int r = id >> 7, k = id & 127;
        xs[k * 36 + r] = X[(long)(m0 + r) * 128 + k];
    }
    __syncthreads();
    int cc = t & 127;
    int sel = t >> 7;  // 0: top (dst-side), 1: bot (src-side)
    const float* pW0 = Wf + (long)sel * 128 * 128 + cc;
    const float* pW1 = Wsp + (long)sel * 128 * 128 + cc;
    float b0 = (sel == 0) ? bf[cc] : 0.0f;
    float b1 = (sel == 0) ? bs[cc] : 0.0f;
    float acc0[32], acc1[32];
#pragma unroll
    for (int r = 0; r < 32; ++r) { acc0[r] = 0.0f; acc1[r] = 0.0f; }
    for (int k = 0; k < 128; ++k) {
        float w0 = pW0[k * 128];
        float w1 = pW1[k * 128];
        const float4* xr = (const float4*)&xs[k * 36];
#pragma unroll
        for (int j = 0; j < 8; ++j) {
            float4 xa = xr[j];
            acc0[4 * j + 0] += xa.x * w0;
            acc0[4 * j + 1] += xa.y * w0;
            acc0[4 * j + 2] += xa.z * w0;
            acc0[4 * j + 3] += xa.w * w0;
            acc1[4 * j + 0] += xa.x * w1;
            acc1[4 * j + 1] += xa.y * w1;
            acc1[4 * j + 2] += xa.z * w1;
            acc1[4 * j + 3] += xa.w * w1;
        }
    }
#pragma unroll
    for (int r = 0; r < 32; ++r) {
        long row = (long)(m0 + r) * 512;
        H[row + sel * 128 + cc] = acc0[r] + b0;        // Fd / Fs
        H[row + 256 + sel * 128 + cc] = acc1[r] + b1;  // Sd / Ss
    }
}

// ---------- bond graph: count edges per dst ----------
__global__ __launch_bounds__(256) void count_kernel(
    const int* __restrict__ dst, int E, float* __restrict__ cnt) {
    int e = blockIdx.x * 256 + threadIdx.x;
    if (e < E) atomicAdd(&cnt[dst[e]], 1.0f);
}

// ---------- bond graph: per-edge gate + atomic aggregate ----------
__global__ __launch_bounds__(256) void edge_bond_kernel(
    const float* __restrict__ H, const int* __restrict__ src,
    const int* __restrict__ dst, int E, float* __restrict__ agg) {
    int e = blockIdx.x * 4 + (threadIdx.x >> 6);
    if (e >= E) return;
    int l = threadIdx.x & 63;
    int s = src[e], d = dst[e];
    const float2* H2 = (const float2*)H;
    long hd = (long)d * 256, hs = (long)s * 256;
    float2 fd = H2[hd + l];
    float2 fs = H2[hs + 64 + l];
    float2 sd = H2[hd + 128 + l];
    float2 ss = H2[hs + 192 + l];
    float fx = fd.x + fs.x, fy = fd.y + fs.y;
    float sx = sd.x + ss.x, sy = sd.y + ss.y;
    float mx = fsigm(fx) * fsoftplus(sx);
    float my = fsigm(fy) * fsoftplus(sy);
    atomicAdd(&agg[(long)d * 128 + 2 * l], mx);
    atomicAdd(&agg[(long)d * 128 + 2 * l + 1], my);
}

// ---------- bond graph: x = relu(x + agg/max(cnt,1)) ----------
__global__ __launch_bounds__(256) void update_bond_kernel(
    float* __restrict__ x, const float* __restrict__ agg,
    const float* __restrict__ cnt) {
    int i = blockIdx.x * 256 + threadIdx.x;
    float c = fmaxf(cnt[i >> 7], 1.0f);
    float v = x[i] + agg[i] * __builtin_amdgcn_rcpf(c);
    x[i] = fmaxf(v, 0.0f);
}

// ---------- radius graph: CSR offsets via binary search (dst is sorted) ----------
__global__ __launch_bounds__(256) void csr_off_kernel(
    const int* __restrict__ dst, int E, int N1, int* __restrict__ off) {
    int n = blockIdx.x * 256 + threadIdx.x;
    if (n >= N1) return;
    int lo = 0, hi = E;
    while (lo < hi) {
        int mid = (lo + hi) >> 1;
        if (dst[mid] < n) lo = mid + 1;
        else hi = mid;
    }
    off[n] = lo;
}

// ---------- radius graph: node-centric gather + fused update ----------
__global__ __launch_bounds__(256) void node_radius_kernel(
    const float* __restrict__ H, const int* __restrict__ src,
    const int* __restrict__ off, const float* __restrict__ xin,
    float* __restrict__ xout) {
    int n = blockIdx.x * 4 + (threadIdx.x >> 6);
    int l = threadIdx.x & 63;
    const float2* H2 = (const float2*)H;
    long hb = (long)n * 256;
    float2 fd = H2[hb + l];
    float2 sd = H2[hb + 128 + l];
    int e0 = off[n], e1 = off[n + 1];
    float ax = 0.0f, ay = 0.0f;
    for (int e = e0; e < e1; ++e) {
        int s = src[e];
        long hs = (long)s * 256;
        float2 fs = H2[hs + 64 + l];
        float2 ss = H2[hs + 192 + l];
        float fx = fd.x + fs.x, fy = fd.y + fs.y;
        float sx = sd.x + ss.x, sy = sd.y + ss.y;
        ax += fsigm(fx) * fsoftplus(sx);
        ay += fsigm(fy) * fsoftplus(sy);
    }
    float inv = __builtin_amdgcn_rcpf(fmaxf((float)(e1 - e0), 1.0f));
    float2 xv = ((const float2*)xin)[(long)n * 64 + l];
    float ox = fmaxf(xv.x + ax * inv, 0.0f);
    float oy = fmaxf(xv.y + ay * inv, 0.0f);
    ((float2*)xout)[(long)n * 64 + l] = make_float2(ox, oy);
}

extern "C" void kernel_launch(void* const* d_in, const int* in_sizes, int n_in,
                              void* d_out, int out_size, void* d_ws, size_t ws_size,
                              hipStream_t stream) {
    const float* x_prot = (const float*)d_in[0];
    // d_in[1] = v_prot (unused)
    const int* eb = (const int*)d_in[2];
    const int* er = (const int*)d_in[3];
    int Eb = in_sizes[2] / 2;
    int Er = in_sizes[3] / 2;
    const float* We1 = (const float*)d_in[4];
    const float* be1 = (const float*)d_in[5];
    const float* We2 = (const float*)d_in[6];
    const float* be2 = (const float*)d_in[7];
    const float* Wf[4]  = {(const float*)d_in[8],  (const float*)d_in[12],
                           (const float*)d_in[16], (const float*)d_in[20]};
    const float* bf[4]  = {(const float*)d_in[9],  (const float*)d_in[13],
                           (const float*)d_in[17], (const float*)d_in[21]};
    const float* Wsp[4] = {(const float*)d_in[10], (const float*)d_in[14],
                           (const float*)d_in[18], (const float*)d_in[22]};
    const float* bsp[4] = {(const float*)d_in[11], (const float*)d_in[15],
                           (const float*)d_in[19], (const float*)d_in[23]};

    char* ws = (char*)d_ws;
    float* xbuf = (float*)ws;                          // N*128 f32 = 10.24 MB
    float* H    = (float*)(ws + 10240000);             // N*512 f32 = 40.96 MB
    float* agg  = (float*)(ws + 10240000 + 40960000);  // N*128 f32 = 10.24 MB
    float* cntb = (float*)(ws + 61440000);             // N f32
    int*   offR = (int*)  (ws + 61440000 + 80000);     // N+1 int

    const int* srcB = eb;
    const int* dstB = eb + Eb;
    const int* srcR = er;
    // dstR = er + Er (sorted by construction of the radius graph)

    // encoder
    enc1_kernel<<<NN, 128, 0, stream>>>(x_prot, We1, be1, agg);
    gemm_nc128_kernel<<<NN / 32, 256, 0, stream>>>(agg, We2, be2, xbuf);

    // per-graph metadata
    hipMemsetAsync(cntb, 0, NN * sizeof(float), stream);
    count_kernel<<<(Eb + 255) / 256, 256, 0, stream>>>(dstB, Eb, cntb);
    csr_off_kernel<<<(NN + 256) / 256, 256, 0, stream>>>(er + Er, Er, NN + 1, offR);

    // layers 1-2: bond graph (atomic aggregation)
    for (int L = 0; L < 2; ++L) {
        proj512_kernel<<<NN / 32, 256, 0, stream>>>(xbuf, Wf[L], Wsp[L], bf[L], bsp[L], H);
        hipMemsetAsync(agg, 0, (size_t)NN * CC * sizeof(float), stream);
        edge_bond_kernel<<<(Eb + 3) / 4, 256, 0, stream>>>(H, srcB, dstB, Eb, agg);
        update_bond_kernel<<<(NN * CC) / 256, 256, 0, stream>>>(xbuf, agg, cntb);
    }
    // layers 3-4: radius graph (node-centric, no atomics)
    for (int L = 2; L < 4; ++L) {
        proj512_kernel<<<NN / 32, 256, 0, stream>>>(xbuf, Wf[L], Wsp[L], bf[L], bsp[L], H);
        float* xout = (L == 3) ? (float*)d_out : xbuf;
        node_radius_kernel<<<NN / 4, 256, 0, stream>>>(H, srcR, offR, xbuf, xout);
    }
    (void)n_in; (void)out_size; (void)ws_size; (void)in_sizes;
}

// Round 2
// 486.911 us; speedup vs baseline: 1.1683x; 1.1683x over previous
//
#include <hip/hip_runtime.h>
#include <hip/hip_bf16.h>

#define NN 20000
#define CC 128

typedef __attribute__((ext_vector_type(8))) _Float16 half8;
typedef __attribute__((ext_vector_type(2))) _Float16 half2v;
typedef __attribute__((ext_vector_type(4))) float f32x4;

// ---------- math helpers ----------
__device__ __forceinline__ float fsigm(float x) {
    float e = __expf(-x);
    return __builtin_amdgcn_rcpf(1.0f + e);
}
__device__ __forceinline__ float fsoftplus(float x) {
    float a = fabsf(x);
    float t = __logf(1.0f + __expf(-a));
    return fmaxf(x, 0.0f) + t;
}

// ---------- weight conversion: proj layers ----------
// Wct[c][k] (f16, 512x128) = column c of combined [Wf_top|Wf_bot|Ws_top|Ws_bot]
__global__ __launch_bounds__(256) void convw_kernel(
    const float* __restrict__ Wf, const float* __restrict__ Ws,
    _Float16* __restrict__ Wct) {
    int id = blockIdx.x * 256 + threadIdx.x;  // 65536
    int c = id & 511;
    int k = id >> 9;
    float v;
    if (c < 128) v = Wf[k * 128 + c];
    else if (c < 256) v = Wf[(128 + k) * 128 + (c - 128)];
    else if (c < 384) v = Ws[k * 128 + (c - 256)];
    else v = Ws[(128 + k) * 128 + (c - 384)];
    Wct[c * 128 + k] = (_Float16)v;
}

// ---------- weight conversion: enc2 (128x128) ----------
__global__ __launch_bounds__(256) void convwe2_kernel(
    const float* __restrict__ W, _Float16* __restrict__ Wct) {
    int id = blockIdx.x * 256 + threadIdx.x;  // 16384
    int c = id & 127;
    int k = id >> 7;
    Wct[c * 128 + k] = (_Float16)W[k * 128 + c];
}

// ---------- encoder layer 1: (N x 32) @ (32 x 128) + b, relu -> f16 ----------
__global__ __launch_bounds__(128) void enc1_kernel(
    const float* __restrict__ xp, const float* __restrict__ W,
    const float* __restrict__ b, _Float16* __restrict__ Y) {
    __shared__ float xs[32];
    int row = blockIdx.x;
    int t = threadIdx.x;
    if (t < 32) xs[t] = xp[(long)row * 32 + t];
    __syncthreads();
    float acc = b[t];
#pragma unroll
    for (int k = 0; k < 32; ++k) acc += xs[k] * W[k * 128 + t];
    Y[(long)row * 128 + t] = (_Float16)fmaxf(acc, 0.0f);
}

// ---------- MFMA GEMM: Y[M x ncol] = A[M x 128] @ W[128 x ncol] ----------
// A f16 row-major; Wt f16 TRANSPOSED [ncol][128].
// mode 0 (proj): outH f16 [M][512]; bias0 on cols [0,128), bias1 on [256,384)
// mode 1 (enc2): ncol=128; outF f32 + outF16 f16; bias0 on all cols
__global__ __launch_bounds__(256) void gemm_mfma_kernel(
    const _Float16* __restrict__ A, const _Float16* __restrict__ Wt,
    const float* __restrict__ bias0, const float* __restrict__ bias1,
    _Float16* __restrict__ outH, float* __restrict__ outF,
    _Float16* __restrict__ outF16, int M, int mode) {
    __shared__ _Float16 As[128 * 128];
    __shared__ _Float16 Bs[128 * 128];
    int t = threadIdx.x;
    int m0 = blockIdx.x * 128;
    int n0 = blockIdx.y * 128;
    // stage: thread t loads chunk c=t&15 (8 f16 = 16B), rows r=(t>>4)+16i
    int c = t & 15;
    int rbase = t >> 4;
    int csw_sh = c ^ (rbase & 7);  // XOR swizzle on chunk index (row&7==rbase&7)
#pragma unroll
    for (int i = 0; i < 8; ++i) {
        int row = rbase + 16 * i;
        int grow = m0 + row;
        half8 va = {0, 0, 0, 0, 0, 0, 0, 0};
        if (grow < M) va = *(const half8*)(A + (long)grow * 128 + c * 8);
        *(half8*)(&As[row * 128 + csw_sh * 8]) = va;
        *(half8*)(&Bs[row * 128 + csw_sh * 8]) =
            *(const half8*)(Wt + (long)(n0 + row) * 128 + c * 8);
    }
    __syncthreads();
    int wid = t >> 6, l = t & 63;
    int wm = wid >> 1, wn = wid & 1;
    int lr = l & 15, hi = l >> 4;
    f32x4 acc[4][4] = {};
#pragma unroll
    for (int ks = 0; ks < 4; ++ks) {
        int cidx = 4 * ks + hi;  // chunk index along K
        half8 af[4], bg[4];
#pragma unroll
        for (int m = 0; m < 4; ++m) {
            int row = wm * 64 + m * 16 + lr;
            af[m] = *(const half8*)(&As[row * 128 + (cidx ^ (lr & 7)) * 8]);
        }
#pragma unroll
        for (int n = 0; n < 4; ++n) {
            int row = wn * 64 + n * 16 + lr;
            bg[n] = *(const half8*)(&Bs[row * 128 + (cidx ^ (lr & 7)) * 8]);
        }
#pragma unroll
        for (int m = 0; m < 4; ++m)
#pragma unroll
            for (int n = 0; n < 4; ++n)
                acc[m][n] = __builtin_amdgcn_mfma_f32_16x16x32_f16(
                    af[m], bg[n], acc[m][n], 0, 0, 0);
    }
    // epilogue: D col = lane&15, row = (lane>>4)*4 + q
#pragma unroll
    for (int n = 0; n < 4; ++n) {
        int gcol = n0 + wn * 64 + n * 16 + lr;
        float badd;
        if (mode == 0) {
            badd = (gcol < 128) ? bias0[gcol]
                 : ((gcol >= 256 && gcol < 384) ? bias1[gcol - 256] : 0.0f);
        } else {
            badd = bias0[gcol];
        }
#pragma unroll
        for (int m = 0; m < 4; ++m) {
#pragma unroll
            for (int q = 0; q < 4; ++q) {
                int grow = m0 + wm * 64 + m * 16 + hi * 4 + q;
                if (grow < M) {
                    float v = acc[m][n][q] + badd;
                    if (mode == 0) {
                        outH[(long)grow * 512 + gcol] = (_Float16)v;
                    } else {
                        outF[(long)grow * 128 + gcol] = v;
                        outF16[(long)grow * 128 + gcol] = (_Float16)v;
                    }
                }
            }
        }
    }
}

// ---------- bond graph: count edges per dst ----------
__global__ __launch_bounds__(256) void count_kernel(
    const int* __restrict__ dst, int E, float* __restrict__ cnt) {
    int e = blockIdx.x * 256 + threadIdx.x;
    if (e < E) atomicAdd(&cnt[dst[e]], 1.0f);
}

// ---------- bond graph: per-edge gate + atomic aggregate (f16 H) ----------
__global__ __launch_bounds__(256) void edge_bond_kernel(
    const _Float16* __restrict__ H, const int* __restrict__ src,
    const int* __restrict__ dst, int E, float* __restrict__ agg) {
    int e = blockIdx.x * 4 + (threadIdx.x >> 6);
    if (e >= E) return;
    int l = threadIdx.x & 63;
    int s = src[e], d = dst[e];
    const half2v* H2 = (const half2v*)H;
    int hd = d * 256, hs = s * 256;
    half2v fd = H2[hd + l];
    half2v fs = H2[hs + 64 + l];
    half2v sd = H2[hd + 128 + l];
    half2v ss = H2[hs + 192 + l];
    float fx = (float)fd.x + (float)fs.x, fy = (float)fd.y + (float)fs.y;
    float sx = (float)sd.x + (float)ss.x, sy = (float)sd.y + (float)ss.y;
    float mx = fsigm(fx) * fsoftplus(sx);
    float my = fsigm(fy) * fsoftplus(sy);
    atomicAdd(&agg[(long)d * 128 + 2 * l], mx);
    atomicAdd(&agg[(long)d * 128 + 2 * l + 1], my);
}

// ---------- bond graph: x = relu(x + agg/max(cnt,1)), dual write ----------
__global__ __launch_bounds__(256) void update_bond_kernel(
    float* __restrict__ x, const float* __restrict__ agg,
    const float* __restrict__ cnt, _Float16* __restrict__ xh) {
    int i = blockIdx.x * 256 + threadIdx.x;
    float cv = fmaxf(cnt[i >> 7], 1.0f);
    float v = fmaxf(x[i] + agg[i] * __builtin_amdgcn_rcpf(cv), 0.0f);
    x[i] = v;
    xh[i] = (_Float16)v;
}

// ---------- radius graph: CSR offsets via binary search (dst sorted) ----------
__global__ __launch_bounds__(256) void csr_off_kernel(
    const int* __restrict__ dst, int E, int N1, int* __restrict__ off) {
    int n = blockIdx.x * 256 + threadIdx.x;
    if (n >= N1) return;
    int lo = 0, hi = E;
    while (lo < hi) {
        int mid = (lo + hi) >> 1;
        if (dst[mid] < n) lo = mid + 1;
        else hi = mid;
    }
    off[n] = lo;
}

// ---------- radius graph: node-centric gather + fused update (f16 H) ----------
__global__ __launch_bounds__(256) void node_radius_kernel(
    const _Float16* __restrict__ H, const int* __restrict__ src,
    const int* __restrict__ off, const float* __restrict__ xin,
    float* __restrict__ xout, _Float16* __restrict__ xh) {
    int n = blockIdx.x * 4 + (threadIdx.x >> 6);
    int l = threadIdx.x & 63;
    const half2v* H2 = (const half2v*)H;
    int hb = n * 256;
    half2v fdh = H2[hb + l];
    half2v sdh = H2[hb + 128 + l];
    float fdx = (float)fdh.x, fdy = (float)fdh.y;
    float sdx = (float)sdh.x, sdy = (float)sdh.y;
    int e0 = off[n], e1 = off[n + 1];
    float ax = 0.0f, ay = 0.0f;
    int e = e0;
    for (; e + 1 < e1; e += 2) {
        int s0 = src[e] * 256, s1 = src[e + 1] * 256;
        half2v fs0 = H2[s0 + 64 + l], ss0 = H2[s0 + 192 + l];
        half2v fs1 = H2[s1 + 64 + l], ss1 = H2[s1 + 192 + l];
        float f0x = fdx + (float)fs0.x, f0y = fdy + (float)fs0.y;
        float s0x = sdx + (float)ss0.x, s0y = sdy + (float)ss0.y;
        float f1x = fdx + (float)fs1.x, f1y = fdy + (float)fs1.y;
        float s1x = sdx + (float)ss1.x, s1y = sdy + (float)ss1.y;
        ax += fsigm(f0x) * fsoftplus(s0x) + fsigm(f1x) * fsoftplus(s1x);
        ay += fsigm(f0y) * fsoftplus(s0y) + fsigm(f1y) * fsoftplus(s1y);
    }
    if (e < e1) {
        int s0 = src[e] * 256;
        half2v fs0 = H2[s0 + 64 + l], ss0 = H2[s0 + 192 + l];
        float f0x = fdx + (float)fs0.x, f0y = fdy + (float)fs0.y;
        float s0x = sdx + (float)ss0.x, s0y = sdy + (float)ss0.y;
        ax += fsigm(f0x) * fsoftplus(s0x);
        ay += fsigm(f0y) * fsoftplus(s0y);
    }
    float inv = __builtin_amdgcn_rcpf(fmaxf((float)(e1 - e0), 1.0f));
    float2 xv = ((const float2*)xin)[(long)n * 64 + l];
    float ox = fmaxf(xv.x + ax * inv, 0.0f);
    float oy = fmaxf(xv.y + ay * inv, 0.0f);
    ((float2*)xout)[(long)n * 64 + l] = make_float2(ox, oy);
    half2v oh;
    oh.x = (_Float16)ox;
    oh.y = (_Float16)oy;
    ((half2v*)xh)[(long)n * 64 + l] = oh;
}

extern "C" void kernel_launch(void* const* d_in, const int* in_sizes, int n_in,
                              void* d_out, int out_size, void* d_ws, size_t ws_size,
                              hipStream_t stream) {
    const float* x_prot = (const float*)d_in[0];
    const int* eb = (const int*)d_in[2];
    const int* er = (const int*)d_in[3];
    int Eb = in_sizes[2] / 2;
    int Er = in_sizes[3] / 2;
    const float* We1 = (const float*)d_in[4];
    const float* be1 = (const float*)d_in[5];
    const float* We2 = (const float*)d_in[6];
    const float* be2 = (const float*)d_in[7];
    const float* Wf[4]  = {(const float*)d_in[8],  (const float*)d_in[12],
                           (const float*)d_in[16], (const float*)d_in[20]};
    const float* bf[4]  = {(const float*)d_in[9],  (const float*)d_in[13],
                           (const float*)d_in[17], (const float*)d_in[21]};
    const float* Wsp[4] = {(const float*)d_in[10], (const float*)d_in[14],
                           (const float*)d_in[18], (const float*)d_in[22]};
    const float* bsp[4] = {(const float*)d_in[11], (const float*)d_in[15],
                           (const float*)d_in[19], (const float*)d_in[23]};

    char* ws = (char*)d_ws;
    float*     xbuf = (float*)ws;                       // 10,240,000 B
    _Float16*  xhf  = (_Float16*)(ws + 10240000);       //  5,120,000 B
    _Float16*  H    = (_Float16*)(ws + 15360000);       // 20,480,000 B
    float*     agg  = (float*)(ws + 35840000);          // 10,240,000 B
    float*     cntb = (float*)(ws + 46080000);          //     80,000 B
    int*       offR = (int*)(ws + 46160000);            //     80,004 B
    _Float16*  Wct0 = (_Float16*)(ws + 46240016);       //    131,072 B each
    _Float16*  Wct1 = (_Float16*)(ws + 46371088);
    _Float16*  Wct2 = (_Float16*)(ws + 46502160);
    _Float16*  Wct3 = (_Float16*)(ws + 46633232);
    _Float16*  Wcte = (_Float16*)(ws + 46764304);       //     32,768 B
    _Float16*  WctL[4] = {Wct0, Wct1, Wct2, Wct3};

    const int* srcB = eb;
    const int* dstB = eb + Eb;
    const int* srcR = er;

    // weight conversions
    for (int L = 0; L < 4; ++L)
        convw_kernel<<<256, 256, 0, stream>>>(Wf[L], Wsp[L], WctL[L]);
    convwe2_kernel<<<64, 256, 0, stream>>>(We2, Wcte);

    // encoder: enc1 -> H (f16 scratch), enc2 via MFMA -> xbuf + xhf
    enc1_kernel<<<NN, 128, 0, stream>>>(x_prot, We1, be1, H);
    {
        dim3 g((NN + 127) / 128, 1);
        gemm_mfma_kernel<<<g, 256, 0, stream>>>(H, Wcte, be2, be2, nullptr,
                                                xbuf, xhf, NN, 1);
    }

    // per-graph metadata
    hipMemsetAsync(cntb, 0, NN * sizeof(float), stream);
    count_kernel<<<(Eb + 255) / 256, 256, 0, stream>>>(dstB, Eb, cntb);
    csr_off_kernel<<<(NN + 256) / 256, 256, 0, stream>>>(er + Er, Er, NN + 1, offR);

    // layers 1-2: bond graph
    for (int L = 0; L < 2; ++L) {
        dim3 g((NN + 127) / 128, 4);
        gemm_mfma_kernel<<<g, 256, 0, stream>>>(xhf, WctL[L], bf[L], bsp[L], H,
                                                nullptr, nullptr, NN, 0);
        hipMemsetAsync(agg, 0, (size_t)NN * CC * sizeof(float), stream);
        edge_bond_kernel<<<(Eb + 3) / 4, 256, 0, stream>>>(H, srcB, dstB, Eb, agg);
        update_bond_kernel<<<(NN * CC) / 256, 256, 0, stream>>>(xbuf, agg, cntb, xhf);
    }
    // layers 3-4: radius graph
    for (int L = 2; L < 4; ++L) {
        dim3 g((NN + 127) / 128, 4);
        gemm_mfma_kernel<<<g, 256, 0, stream>>>(xhf, WctL[L], bf[L], bsp[L], H,
                                                nullptr, nullptr, NN, 0);
        float* xout = (L == 3) ? (float*)d_out : xbuf;
        node_radius_kernel<<<NN / 4, 256, 0, stream>>>(H, srcR, offR, xbuf, xout, xhf);
    }
    (void)n_in; (void)out_size; (void)ws_size;
}

// Round 3
// 358.151 us; speedup vs baseline: 1.5883x; 1.3595x over previous
//
#include <hip/hip_runtime.h>
#include <hip/hip_bf16.h>

#define NN 20000
#define CC 128

typedef __attribute__((ext_vector_type(8))) _Float16 half8;
typedef __attribute__((ext_vector_type(2))) _Float16 half2v;
typedef __attribute__((ext_vector_type(4))) float f32x4;

// ---------- math helpers ----------
__device__ __forceinline__ float fsigm(float x) {
    float e = __expf(-x);
    return __builtin_amdgcn_rcpf(1.0f + e);
}
__device__ __forceinline__ float fsoftplus(float x) {
    float a = fabsf(x);
    float t = __logf(1.0f + __expf(-a));
    return fmaxf(x, 0.0f) + t;
}

// ---------- one-shot conversions: proj weights, We2, We1^T, x_prot->f16 ----------
__global__ __launch_bounds__(256) void conv_all_kernel(
    const float* __restrict__ Wf0, const float* __restrict__ Ws0,
    const float* __restrict__ Wf1, const float* __restrict__ Ws1,
    const float* __restrict__ Wf2, const float* __restrict__ Ws2,
    const float* __restrict__ Wf3, const float* __restrict__ Ws3,
    const float* __restrict__ We2, const float* __restrict__ We1,
    const float* __restrict__ xprot,
    _Float16* __restrict__ WctAll, _Float16* __restrict__ Wcte,
    _Float16* __restrict__ Wt1, _Float16* __restrict__ xp16) {
    int id = blockIdx.x * 256 + threadIdx.x;
    if (id < 262144) {
        int Lw = id >> 16;
        int i = id & 65535;
        int c = i & 511;
        int k = i >> 9;
        const float* Wfp = (Lw == 0) ? Wf0 : (Lw == 1) ? Wf1 : (Lw == 2) ? Wf2 : Wf3;
        const float* Wsp = (Lw == 0) ? Ws0 : (Lw == 1) ? Ws1 : (Lw == 2) ? Ws2 : Ws3;
        float v;
        if (c < 128) v = Wfp[k * 128 + c];
        else if (c < 256) v = Wfp[(128 + k) * 128 + (c - 128)];
        else if (c < 384) v = Wsp[k * 128 + (c - 256)];
        else v = Wsp[(128 + k) * 128 + (c - 384)];
        WctAll[Lw * 65536 + c * 128 + k] = (_Float16)v;
    } else if (id < 278528) {
        int i = id - 262144;
        int c = i & 127;
        int k = i >> 7;
        Wcte[c * 128 + k] = (_Float16)We2[k * 128 + c];
    } else if (id < 282624) {
        int i = id - 278528;
        int c = i & 127;
        int k = i >> 7;  // k < 32
        Wt1[c * 32 + k] = (_Float16)We1[k * 128 + c];
    } else {
        int i = id - 282624;  // < 640000
        xp16[i] = (_Float16)xprot[i];
    }
}

// ---------- encoder layer 1 via MFMA: (N x 32) @ (32 x 128) + b, relu -> f16 ----------
__global__ __launch_bounds__(256) void enc1_mfma_kernel(
    const _Float16* __restrict__ A, const _Float16* __restrict__ Wt1,
    const float* __restrict__ b, _Float16* __restrict__ Y) {
    int t = threadIdx.x;
    int wid = t >> 6, l = t & 63;
    int lr = l & 15, hi = l >> 4;
    int m0 = blockIdx.x * 128 + wid * 32;
    half8 af[2];
#pragma unroll
    for (int m = 0; m < 2; ++m) {
        int row = m0 + m * 16 + lr;
        half8 v = {0, 0, 0, 0, 0, 0, 0, 0};
        if (row < NN) v = *(const half8*)(A + (long)row * 32 + hi * 8);
        af[m] = v;
    }
    f32x4 acc[2][8] = {};
#pragma unroll
    for (int n = 0; n < 8; ++n) {
        int col = n * 16 + lr;
        half8 bg = *(const half8*)(Wt1 + (long)col * 32 + hi * 8);
#pragma unroll
        for (int m = 0; m < 2; ++m)
            acc[m][n] = __builtin_amdgcn_mfma_f32_16x16x32_f16(af[m], bg, acc[m][n], 0, 0, 0);
    }
#pragma unroll
    for (int n = 0; n < 8; ++n) {
        int col = n * 16 + lr;
        float bb = b[col];
#pragma unroll
        for (int m = 0; m < 2; ++m) {
#pragma unroll
            for (int q = 0; q < 4; ++q) {
                int row = m0 + m * 16 + hi * 4 + q;
                if (row < NN)
                    Y[(long)row * 128 + col] = (_Float16)fmaxf(acc[m][n][q] + bb, 0.0f);
            }
        }
    }
}

// ---------- MFMA GEMM: Y[M x ncol] = A[M x 128] @ W[128 x ncol] ----------
__global__ __launch_bounds__(256) void gemm_mfma_kernel(
    const _Float16* __restrict__ A, const _Float16* __restrict__ Wt,
    const float* __restrict__ bias0, const float* __restrict__ bias1,
    _Float16* __restrict__ outH, float* __restrict__ outF,
    _Float16* __restrict__ outF16, int M, int mode) {
    __shared__ _Float16 As[128 * 128];
    __shared__ _Float16 Bs[128 * 128];
    int t = threadIdx.x;
    int m0 = blockIdx.x * 128;
    int n0 = blockIdx.y * 128;
    int c = t & 15;
    int rbase = t >> 4;
    int csw_sh = c ^ (rbase & 7);
#pragma unroll
    for (int i = 0; i < 8; ++i) {
        int row = rbase + 16 * i;
        int grow = m0 + row;
        half8 va = {0, 0, 0, 0, 0, 0, 0, 0};
        if (grow < M) va = *(const half8*)(A + (long)grow * 128 + c * 8);
        *(half8*)(&As[row * 128 + csw_sh * 8]) = va;
        *(half8*)(&Bs[row * 128 + csw_sh * 8]) =
            *(const half8*)(Wt + (long)(n0 + row) * 128 + c * 8);
    }
    __syncthreads();
    int wid = t >> 6, l = t & 63;
    int wm = wid >> 1, wn = wid & 1;
    int lr = l & 15, hi = l >> 4;
    f32x4 acc[4][4] = {};
#pragma unroll
    for (int ks = 0; ks < 4; ++ks) {
        int cidx = 4 * ks + hi;
        half8 af[4], bg[4];
#pragma unroll
        for (int m = 0; m < 4; ++m) {
            int row = wm * 64 + m * 16 + lr;
            af[m] = *(const half8*)(&As[row * 128 + (cidx ^ (lr & 7)) * 8]);
        }
#pragma unroll
        for (int n = 0; n < 4; ++n) {
            int row = wn * 64 + n * 16 + lr;
            bg[n] = *(const half8*)(&Bs[row * 128 + (cidx ^ (lr & 7)) * 8]);
        }
#pragma unroll
        for (int m = 0; m < 4; ++m)
#pragma unroll
            for (int n = 0; n < 4; ++n)
                acc[m][n] = __builtin_amdgcn_mfma_f32_16x16x32_f16(
                    af[m], bg[n], acc[m][n], 0, 0, 0);
    }
#pragma unroll
    for (int n = 0; n < 4; ++n) {
        int gcol = n0 + wn * 64 + n * 16 + lr;
        float badd;
        if (mode == 0) {
            badd = (gcol < 128) ? bias0[gcol]
                 : ((gcol >= 256 && gcol < 384) ? bias1[gcol - 256] : 0.0f);
        } else {
            badd = bias0[gcol];
        }
#pragma unroll
        for (int m = 0; m < 4; ++m) {
#pragma unroll
            for (int q = 0; q < 4; ++q) {
                int grow = m0 + wm * 64 + m * 16 + hi * 4 + q;
                if (grow < M) {
                    float v = acc[m][n][q] + badd;
                    if (mode == 0) {
                        outH[(long)grow * 512 + gcol] = (_Float16)v;
                    } else {
                        outF[(long)grow * 128 + gcol] = v;
                        outF16[(long)grow * 128 + gcol] = (_Float16)v;
                    }
                }
            }
        }
    }
}

// ---------- bond CSR build ----------
__global__ __launch_bounds__(256) void count_int_kernel(
    const int* __restrict__ dst, int E, int* __restrict__ cnt) {
    int e = blockIdx.x * 256 + threadIdx.x;
    if (e < E) atomicAdd(&cnt[dst[e]], 1);
}

__global__ __launch_bounds__(1024) void scan_kernel(
    const int* __restrict__ cnt, int* __restrict__ off) {
    __shared__ int part[1024];
    int t = threadIdx.x;
    int base = t * 20;
    int loc[20];
    int s = 0;
#pragma unroll
    for (int i = 0; i < 20; ++i) {
        int idx = base + i;
        int v = (idx < NN) ? cnt[idx] : 0;
        loc[i] = s;
        s += v;
    }
    part[t] = s;
    __syncthreads();
    for (int d = 1; d < 1024; d <<= 1) {
        int v = (t >= d) ? part[t - d] : 0;
        __syncthreads();
        part[t] += v;
        __syncthreads();
    }
    int pre = (t > 0) ? part[t - 1] : 0;
#pragma unroll
    for (int i = 0; i < 20; ++i) {
        int idx = base + i;
        if (idx < NN) off[idx] = pre + loc[i];
    }
    if (t == 1023) off[NN] = part[1023];
}

__global__ __launch_bounds__(256) void scatter_kernel(
    const int* __restrict__ src, const int* __restrict__ dst, int E,
    const int* __restrict__ off, int* __restrict__ cur, int* __restrict__ eid) {
    int e = blockIdx.x * 256 + threadIdx.x;
    if (e < E) {
        int d = dst[e];
        int p = off[d] + atomicAdd(&cur[d], 1);
        eid[p] = src[e];
    }
}

// ---------- radius CSR offsets via binary search (dst sorted) ----------
__global__ __launch_bounds__(256) void csr_off_kernel(
    const int* __restrict__ dst, int E, int N1, int* __restrict__ off) {
    int n = blockIdx.x * 256 + threadIdx.x;
    if (n >= N1) return;
    int lo = 0, hi = E;
    while (lo < hi) {
        int mid = (lo + hi) >> 1;
        if (dst[mid] < n) lo = mid + 1;
        else hi = mid;
    }
    off[n] = lo;
}

// ---------- unified node-centric aggregation + fused update ----------
// wave per node; scalarized edge loop (readfirstlane -> s_load for src list)
__global__ __launch_bounds__(256) void node_agg_kernel(
    const _Float16* __restrict__ H, const int* __restrict__ srcArr,
    const int* __restrict__ off, const float* __restrict__ xin,
    float* __restrict__ xout, _Float16* __restrict__ xh, int write_h) {
    int n = blockIdx.x * 4 + (threadIdx.x >> 6);
    int nu = __builtin_amdgcn_readfirstlane(n);
    int l = threadIdx.x & 63;
    const half2v* H2 = (const half2v*)H;
    const half2v* hrow = H2 + (long)nu * 256;
    half2v fdh = hrow[l];
    half2v sdh = hrow[128 + l];
    float fdx = (float)fdh.x, fdy = (float)fdh.y;
    float sdx = (float)sdh.x, sdy = (float)sdh.y;
    int e0 = __builtin_amdgcn_readfirstlane(off[nu]);
    int e1 = __builtin_amdgcn_readfirstlane(off[nu + 1]);
    float ax = 0.0f, ay = 0.0f;
#define EDGEC(fv, sv)                                                  \
    {                                                                  \
        float fx = fdx + (float)(fv).x, fy = fdy + (float)(fv).y;      \
        float sx = sdx + (float)(sv).x, sy = sdy + (float)(sv).y;      \
        ax += fsigm(fx) * fsoftplus(sx);                               \
        ay += fsigm(fy) * fsoftplus(sy);                               \
    }
    int e = e0;
    for (; e + 3 < e1; e += 4) {
        int s0 = srcArr[e], s1 = srcArr[e + 1];
        int s2 = srcArr[e + 2], s3 = srcArr[e + 3];
        const half2v* h0 = H2 + (long)s0 * 256;
        const half2v* h1 = H2 + (long)s1 * 256;
        const half2v* h2 = H2 + (long)s2 * 256;
        const half2v* h3 = H2 + (long)s3 * 256;
        half2v f0 = h0[64 + l], g0 = h0[192 + l];
        half2v f1 = h1[64 + l], g1 = h1[192 + l];
        half2v f2 = h2[64 + l], g2 = h2[192 + l];
        half2v f3 = h3[64 + l], g3 = h3[192 + l];
        EDGEC(f0, g0) EDGEC(f1, g1) EDGEC(f2, g2) EDGEC(f3, g3)
    }
    for (; e < e1; ++e) {
        int s0 = srcArr[e];
        const half2v* h0 = H2 + (long)s0 * 256;
        half2v f0 = h0[64 + l], g0 = h0[192 + l];
        EDGEC(f0, g0)
    }
#undef EDGEC
    float inv = __builtin_amdgcn_rcpf(fmaxf((float)(e1 - e0), 1.0f));
    float2 xv = ((const float2*)xin)[(long)nu * 64 + l];
    float ox = fmaxf(xv.x + ax * inv, 0.0f);
    float oy = fmaxf(xv.y + ay * inv, 0.0f);
    ((float2*)xout)[(long)nu * 64 + l] = make_float2(ox, oy);
    if (write_h) {
        half2v oh;
        oh.x = (_Float16)ox;
        oh.y = (_Float16)oy;
        ((half2v*)xh)[(long)nu * 64 + l] = oh;
    }
}

extern "C" void kernel_launch(void* const* d_in, const int* in_sizes, int n_in,
                              void* d_out, int out_size, void* d_ws, size_t ws_size,
                              hipStream_t stream) {
    const float* x_prot = (const float*)d_in[0];
    const int* eb = (const int*)d_in[2];
    const int* er = (const int*)d_in[3];
    int Eb = in_sizes[2] / 2;
    int Er = in_sizes[3] / 2;
    const float* We1 = (const float*)d_in[4];
    const float* be1 = (const float*)d_in[5];
    const float* We2 = (const float*)d_in[6];
    const float* be2 = (const float*)d_in[7];
    const float* Wf[4]  = {(const float*)d_in[8],  (const float*)d_in[12],
                           (const float*)d_in[16], (const float*)d_in[20]};
    const float* bf[4]  = {(const float*)d_in[9],  (const float*)d_in[13],
                           (const float*)d_in[17], (const float*)d_in[21]};
    const float* Wsp[4] = {(const float*)d_in[10], (const float*)d_in[14],
                           (const float*)d_in[18], (const float*)d_in[22]};
    const float* bsp[4] = {(const float*)d_in[11], (const float*)d_in[15],
                           (const float*)d_in[19], (const float*)d_in[23]};

    char* ws = (char*)d_ws;
    float*     xbuf  = (float*)ws;                        // 10,240,000
    _Float16*  xhf   = (_Float16*)(ws + 10240000);        //  5,120,000
    _Float16*  H     = (_Float16*)(ws + 15360000);        // 20,480,000
    _Float16*  xp16  = (_Float16*)(ws + 35840000);        //  1,280,000
    int*       cntI  = (int*)(ws + 37120000);             //     80,000
    int*       curB  = (int*)(ws + 37200000);             //     80,000
    int*       offB  = (int*)(ws + 37280000);             //     80,016
    int*       offR  = (int*)(ws + 37360016);             //     80,016
    int*       eidB  = (int*)(ws + 37440032);             //    320,000
    _Float16*  WctAll= (_Float16*)(ws + 37760032);        //    524,288
    _Float16*  Wcte  = (_Float16*)(ws + 38284320);        //     32,768
    _Float16*  Wt1   = (_Float16*)(ws + 38317088);        //      8,192

    const int* srcB = eb;
    const int* dstB = eb + Eb;
    const int* srcR = er;

    // conversions (one kernel)
    conv_all_kernel<<<3604, 256, 0, stream>>>(
        Wf[0], Wsp[0], Wf[1], Wsp[1], Wf[2], Wsp[2], Wf[3], Wsp[3],
        We2, We1, x_prot, WctAll, Wcte, Wt1, xp16);

    // bond CSR build + radius CSR offsets
    hipMemsetAsync(cntI, 0, 160000, stream);  // cntI + curB contiguous
    count_int_kernel<<<(Eb + 255) / 256, 256, 0, stream>>>(dstB, Eb, cntI);
    scan_kernel<<<1, 1024, 0, stream>>>(cntI, offB);
    scatter_kernel<<<(Eb + 255) / 256, 256, 0, stream>>>(srcB, dstB, Eb, offB, curB, eidB);
    csr_off_kernel<<<(NN + 256) / 256, 256, 0, stream>>>(er + Er, Er, NN + 1, offR);

    // encoder
    enc1_mfma_kernel<<<157, 256, 0, stream>>>(xp16, Wt1, be1, H);
    {
        dim3 g(157, 1);
        gemm_mfma_kernel<<<g, 256, 0, stream>>>(H, Wcte, be2, be2, nullptr,
                                                xbuf, xhf, NN, 1);
    }

    // 4 CGConv layers (0-1: bond CSR, 2-3: radius CSR)
    for (int L = 0; L < 4; ++L) {
        dim3 g(157, 4);
        gemm_mfma_kernel<<<g, 256, 0, stream>>>(xhf, WctAll + L * 65536, bf[L],
                                                bsp[L], H, nullptr, nullptr, NN, 0);
        const int* sArr = (L < 2) ? eidB : srcR;
        const int* oArr = (L < 2) ? offB : offR;
        float* xout = (L == 3) ? (float*)d_out : xbuf;
        node_agg_kernel<<<NN / 4, 256, 0, stream>>>(H, sArr, oArr, xbuf, xout,
                                                    xhf, (L == 3) ? 0 : 1);
    }
    (void)n_in; (void)out_size; (void)ws_size;
}

// Round 4
// 230.404 us; speedup vs baseline: 2.4690x; 1.5544x over previous
//
#include <hip/hip_runtime.h>
#include <hip/hip_bf16.h>

#define NN 20000
#define CC 128

typedef __attribute__((ext_vector_type(8))) _Float16 half8;
typedef __attribute__((ext_vector_type(2))) _Float16 half2v;
typedef __attribute__((ext_vector_type(4))) float f32x4;

typedef const __attribute__((address_space(1))) void gv_t;
typedef __attribute__((address_space(3))) void sv_t;

// ---------- one-shot conversions: proj weights, We2, We1^T, x_prot->f16 ----------
__global__ __launch_bounds__(256) void conv_all_kernel(
    const float* __restrict__ Wf0, const float* __restrict__ Ws0,
    const float* __restrict__ Wf1, const float* __restrict__ Ws1,
    const float* __restrict__ Wf2, const float* __restrict__ Ws2,
    const float* __restrict__ Wf3, const float* __restrict__ Ws3,
    const float* __restrict__ We2, const float* __restrict__ We1,
    const float* __restrict__ xprot,
    _Float16* __restrict__ WctAll, _Float16* __restrict__ Wcte,
    _Float16* __restrict__ Wt1, _Float16* __restrict__ xp16) {
    int id = blockIdx.x * 256 + threadIdx.x;
    if (id < 262144) {
        int Lw = id >> 16;
        int i = id & 65535;
        int c = i & 511;
        int k = i >> 9;
        const float* Wfp = (Lw == 0) ? Wf0 : (Lw == 1) ? Wf1 : (Lw == 2) ? Wf2 : Wf3;
        const float* Wsp = (Lw == 0) ? Ws0 : (Lw == 1) ? Ws1 : (Lw == 2) ? Ws2 : Ws3;
        float v;
        if (c < 128) v = Wfp[k * 128 + c];
        else if (c < 256) v = Wfp[(128 + k) * 128 + (c - 128)];
        else if (c < 384) v = Wsp[k * 128 + (c - 256)];
        else v = Wsp[(128 + k) * 128 + (c - 384)];
        WctAll[Lw * 65536 + c * 128 + k] = (_Float16)v;
    } else if (id < 278528) {
        int i = id - 262144;
        int c = i & 127;
        int k = i >> 7;
        Wcte[c * 128 + k] = (_Float16)We2[k * 128 + c];
    } else if (id < 282624) {
        int i = id - 278528;
        int c = i & 127;
        int k = i >> 7;  // k < 32
        Wt1[c * 32 + k] = (_Float16)We1[k * 128 + c];
    } else {
        int i = id - 282624;  // < 640000
        xp16[i] = (_Float16)xprot[i];
    }
}

// ---------- encoder layer 1 via MFMA: (N x 32) @ (32 x 128) + b, relu -> f16 ----------
__global__ __launch_bounds__(256) void enc1_mfma_kernel(
    const _Float16* __restrict__ A, const _Float16* __restrict__ Wt1,
    const float* __restrict__ b, _Float16* __restrict__ Y) {
    int t = threadIdx.x;
    int wid = t >> 6, l = t & 63;
    int lr = l & 15, hi = l >> 4;
    int m0 = blockIdx.x * 128 + wid * 32;
    half8 af[2];
#pragma unroll
    for (int m = 0; m < 2; ++m) {
        int row = m0 + m * 16 + lr;
        half8 v = {0, 0, 0, 0, 0, 0, 0, 0};
        if (row < NN) v = *(const half8*)(A + (long)row * 32 + hi * 8);
        af[m] = v;
    }
    f32x4 acc[2][8] = {};
#pragma unroll
    for (int n = 0; n < 8; ++n) {
        int col = n * 16 + lr;
        half8 bg = *(const half8*)(Wt1 + (long)col * 32 + hi * 8);
#pragma unroll
        for (int m = 0; m < 2; ++m)
            acc[m][n] = __builtin_amdgcn_mfma_f32_16x16x32_f16(af[m], bg, acc[m][n], 0, 0, 0);
    }
#pragma unroll
    for (int n = 0; n < 8; ++n) {
        int col = n * 16 + lr;
        float bb = b[col];
#pragma unroll
        for (int m = 0; m < 2; ++m) {
#pragma unroll
            for (int q = 0; q < 4; ++q) {
                int row = m0 + m * 16 + hi * 4 + q;
                if (row < NN)
                    Y[(long)row * 128 + col] = (_Float16)fmaxf(acc[m][n][q] + bb, 0.0f);
            }
        }
    }
}

// ---------- MFMA GEMM: Y[M x ncol] = A[M x 128] @ W[128 x ncol] ----------
// A f16 row-major; Wt f16 TRANSPOSED [ncol][128].
// mode 0 (proj): outH f16 [M][512] scaled by log2(e); bias0 on [0,128), bias1 on [256,384)
// mode 1 (enc2): ncol=128; outF f32 + outF16 f16 (unscaled); bias0 on all cols
__global__ __launch_bounds__(256) void gemm_mfma_kernel(
    const _Float16* __restrict__ A, const _Float16* __restrict__ Wt,
    const float* __restrict__ bias0, const float* __restrict__ bias1,
    _Float16* __restrict__ outH, float* __restrict__ outF,
    _Float16* __restrict__ outF16, int M, int mode) {
    __shared__ _Float16 lds[32768];  // 64 KB: A tile [0,16384), B tile [16384,32768)
    int t = threadIdx.x;
    int w = t >> 6, l = t & 63;
    int m0 = blockIdx.x * 128;
    int n0 = blockIdx.y * 128;
    // stage via global_load_lds width=16; LDS linear, source pre-swizzled.
    {
        int rin = l >> 4;   // 0..3
        int cs = l & 15;    // lds chunk slot
#pragma unroll
        for (int j = 0; j < 8; ++j) {
            int r = w * 32 + j * 4 + rin;
            int g = cs ^ (r & 7);  // global chunk to land in slot cs
            int grow = m0 + r;
            if (grow > M - 1) grow = M - 1;
            const _Float16* srcA = A + (long)grow * 128 + g * 8;
            __builtin_amdgcn_global_load_lds((gv_t*)srcA,
                (sv_t*)&lds[(w * 32 + j * 4) * 128], 16, 0, 0);
            const _Float16* srcB = Wt + (long)(n0 + r) * 128 + g * 8;
            __builtin_amdgcn_global_load_lds((gv_t*)srcB,
                (sv_t*)&lds[16384 + (w * 32 + j * 4) * 128], 16, 0, 0);
        }
    }
    __syncthreads();
    int wm = w >> 1, wn = w & 1;
    int lr = l & 15, hi = l >> 4;
    f32x4 acc[4][4] = {};
#pragma unroll
    for (int ks = 0; ks < 4; ++ks) {
        int cidx = 4 * ks + hi;
        half8 af[4], bg[4];
#pragma unroll
        for (int m = 0; m < 4; ++m) {
            int row = wm * 64 + m * 16 + lr;
            af[m] = *(const half8*)(&lds[row * 128 + (cidx ^ (row & 7)) * 8]);
        }
#pragma unroll
        for (int n = 0; n < 4; ++n) {
            int row = wn * 64 + n * 16 + lr;
            bg[n] = *(const half8*)(&lds[16384 + row * 128 + (cidx ^ (row & 7)) * 8]);
        }
#pragma unroll
        for (int m = 0; m < 4; ++m)
#pragma unroll
            for (int n = 0; n < 4; ++n)
                acc[m][n] = __builtin_amdgcn_mfma_f32_16x16x32_f16(
                    af[m], bg[n], acc[m][n], 0, 0, 0);
    }
    if (mode == 0) {
        // epilogue: bias + *log2e -> LDS [128][144] f16 -> wide coalesced stores
        __syncthreads();
        const float S = 1.44269504f;
#pragma unroll
        for (int n = 0; n < 4; ++n) {
            int cl = wn * 64 + n * 16 + lr;
            int gcol = n0 + cl;
            float badd = (gcol < 128) ? bias0[gcol]
                       : ((gcol >= 256 && gcol < 384) ? bias1[gcol - 256] : 0.0f);
#pragma unroll
            for (int m = 0; m < 4; ++m)
#pragma unroll
                for (int q = 0; q < 4; ++q) {
                    int rl = wm * 64 + m * 16 + hi * 4 + q;
                    lds[rl * 144 + cl] = (_Float16)((acc[m][n][q] + badd) * S);
                }
        }
        __syncthreads();
#pragma unroll
        for (int i = 0; i < 8; ++i) {
            int id = t + 256 * i;
            int row = id >> 4, ch = id & 15;
            int grow = m0 + row;
            if (grow < M) {
                half8 v = *(const half8*)(&lds[row * 144 + ch * 8]);
                *(half8*)(&outH[(long)grow * 512 + n0 + ch * 8]) = v;
            }
        }
    } else {
#pragma unroll
        for (int n = 0; n < 4; ++n) {
            int gcol = n0 + wn * 64 + n * 16 + lr;
            float badd = bias0[gcol];
#pragma unroll
            for (int m = 0; m < 4; ++m)
#pragma unroll
                for (int q = 0; q < 4; ++q) {
                    int grow = m0 + wm * 64 + m * 16 + hi * 4 + q;
                    if (grow < M) {
                        float v = acc[m][n][q] + badd;
                        outF[(long)grow * 128 + gcol] = v;
                        outF16[(long)grow * 128 + gcol] = (_Float16)v;
                    }
                }
        }
    }
}

// ---------- bond CSR build ----------
__global__ __launch_bounds__(256) void count_int_kernel(
    const int* __restrict__ dst, int E, int* __restrict__ cnt) {
    int e = blockIdx.x * 256 + threadIdx.x;
    if (e < E) atomicAdd(&cnt[dst[e]], 1);
}

__global__ __launch_bounds__(1024) void scan_kernel(
    const int* __restrict__ cnt, int* __restrict__ off) {
    __shared__ int part[1024];
    int t = threadIdx.x;
    int base = t * 20;
    int loc[20];
    int s = 0;
#pragma unroll
    for (int i = 0; i < 20; ++i) {
        int idx = base + i;
        int v = (idx < NN) ? cnt[idx] : 0;
        loc[i] = s;
        s += v;
    }
    part[t] = s;
    __syncthreads();
    for (int d = 1; d < 1024; d <<= 1) {
        int v = (t >= d) ? part[t - d] : 0;
        __syncthreads();
        part[t] += v;
        __syncthreads();
    }
    int pre = (t > 0) ? part[t - 1] : 0;
#pragma unroll
    for (int i = 0; i < 20; ++i) {
        int idx = base + i;
        if (idx < NN) off[idx] = pre + loc[i];
    }
    if (t == 1023) off[NN] = part[1023];
}

__global__ __launch_bounds__(256) void scatter_kernel(
    const int* __restrict__ src, const int* __restrict__ dst, int E,
    const int* __restrict__ off, int* __restrict__ cur, int* __restrict__ eid) {
    int e = blockIdx.x * 256 + threadIdx.x;
    if (e < E) {
        int d = dst[e];
        int p = off[d] + atomicAdd(&cur[d], 1);
        eid[p] = src[e];
    }
}

// ---------- radius CSR offsets via binary search (dst sorted) ----------
__global__ __launch_bounds__(256) void csr_off_kernel(
    const int* __restrict__ dst, int E, int N1, int* __restrict__ off) {
    int n = blockIdx.x * 256 + threadIdx.x;
    if (n >= N1) return;
    int lo = 0, hi = E;
    while (lo < hi) {
        int mid = (lo + hi) >> 1;
        if (dst[mid] < n) lo = mid + 1;
        else hi = mid;
    }
    off[n] = lo;
}

// ---------- unified node-centric aggregation + fused update ----------
// H is pre-scaled by log2(e); gate math in exp2/log2 domain, ln2 folded into inv.
__global__ __launch_bounds__(256) void node_agg_kernel(
    const _Float16* __restrict__ H, const int* __restrict__ srcArr,
    const int* __restrict__ off, const float* __restrict__ xin,
    float* __restrict__ xout, _Float16* __restrict__ xh, int write_h) {
    int n = blockIdx.x * 4 + (threadIdx.x >> 6);
    int nu = __builtin_amdgcn_readfirstlane(n);
    int l = threadIdx.x & 63;
    const half2v* H2 = (const half2v*)H;
    const half2v* hrow = H2 + (long)nu * 256;
    half2v fdh = hrow[l];
    half2v sdh = hrow[128 + l];
    int e0 = __builtin_amdgcn_readfirstlane(off[nu]);
    int e1 = __builtin_amdgcn_readfirstlane(off[nu + 1]);
    float ax = 0.0f, ay = 0.0f;
#define EDGEC(fv, sv)                                                        \
    {                                                                        \
        half2v fsum = fdh + (fv);                                            \
        half2v ssum = sdh + (sv);                                            \
        float fx = (float)fsum.x, fy = (float)fsum.y;                        \
        float sx = (float)ssum.x, sy = (float)ssum.y;                        \
        float rx = __builtin_amdgcn_rcpf(1.0f + __builtin_amdgcn_exp2f(-fx)); \
        float ry = __builtin_amdgcn_rcpf(1.0f + __builtin_amdgcn_exp2f(-fy)); \
        float spx = fmaxf(sx, 0.0f) +                                        \
                    __builtin_amdgcn_logf(1.0f + __builtin_amdgcn_exp2f(-fabsf(sx))); \
        float spy = fmaxf(sy, 0.0f) +                                        \
                    __builtin_amdgcn_logf(1.0f + __builtin_amdgcn_exp2f(-fabsf(sy))); \
        ax += rx * spx;                                                      \
        ay += ry * spy;                                                      \
    }
    int e = e0;
    for (; e + 3 < e1; e += 4) {
        int s0 = srcArr[e], s1 = srcArr[e + 1];
        int s2 = srcArr[e + 2], s3 = srcArr[e + 3];
        const half2v* h0 = H2 + (long)s0 * 256;
        const half2v* h1 = H2 + (long)s1 * 256;
        const half2v* h2 = H2 + (long)s2 * 256;
        const half2v* h3 = H2 + (long)s3 * 256;
        half2v f0 = h0[64 + l], g0 = h0[192 + l];
        half2v f1 = h1[64 + l], g1 = h1[192 + l];
        half2v f2 = h2[64 + l], g2 = h2[192 + l];
        half2v f3 = h3[64 + l], g3 = h3[192 + l];
        EDGEC(f0, g0) EDGEC(f1, g1) EDGEC(f2, g2) EDGEC(f3, g3)
    }
    for (; e < e1; ++e) {
        int s0 = srcArr[e];
        const half2v* h0 = H2 + (long)s0 * 256;
        half2v f0 = h0[64 + l], g0 = h0[192 + l];
        EDGEC(f0, g0)
    }
#undef EDGEC
    // inv = ln2 / cnt  (folds softplus' ln2 back in)
    float inv = 0.6931471805599453f *
                __builtin_amdgcn_rcpf(fmaxf((float)(e1 - e0), 1.0f));
    float2 xv = ((const float2*)xin)[(long)nu * 64 + l];
    float ox = fmaxf(xv.x + ax * inv, 0.0f);
    float oy = fmaxf(xv.y + ay * inv, 0.0f);
    ((float2*)xout)[(long)nu * 64 + l] = make_float2(ox, oy);
    if (write_h) {
        half2v oh;
        oh.x = (_Float16)ox;
        oh.y = (_Float16)oy;
        ((half2v*)xh)[(long)nu * 64 + l] = oh;
    }
}

extern "C" void kernel_launch(void* const* d_in, const int* in_sizes, int n_in,
                              void* d_out, int out_size, void* d_ws, size_t ws_size,
                              hipStream_t stream) {
    const float* x_prot = (const float*)d_in[0];
    const int* eb = (const int*)d_in[2];
    const int* er = (const int*)d_in[3];
    int Eb = in_sizes[2] / 2;
    int Er = in_sizes[3] / 2;
    const float* We1 = (const float*)d_in[4];
    const float* be1 = (const float*)d_in[5];
    const float* We2 = (const float*)d_in[6];
    const float* be2 = (const float*)d_in[7];
    const float* Wf[4]  = {(const float*)d_in[8],  (const float*)d_in[12],
                           (const float*)d_in[16], (const float*)d_in[20]};
    const float* bf[4]  = {(const float*)d_in[9],  (const float*)d_in[13],
                           (const float*)d_in[17], (const float*)d_in[21]};
    const float* Wsp[4] = {(const float*)d_in[10], (const float*)d_in[14],
                           (const float*)d_in[18], (const float*)d_in[22]};
    const float* bsp[4] = {(const float*)d_in[11], (const float*)d_in[15],
                           (const float*)d_in[19], (const float*)d_in[23]};

    char* ws = (char*)d_ws;
    float*     xbuf  = (float*)ws;                        // 10,240,000
    _Float16*  xhf   = (_Float16*)(ws + 10240000);        //  5,120,000
    _Float16*  H     = (_Float16*)(ws + 15360000);        // 20,480,000
    _Float16*  xp16  = (_Float16*)(ws + 35840000);        //  1,280,000
    int*       cntI  = (int*)(ws + 37120000);             //     80,000
    int*       curB  = (int*)(ws + 37200000);             //     80,000
    int*       offB  = (int*)(ws + 37280000);             //     80,016
    int*       offR  = (int*)(ws + 37360016);             //     80,016
    int*       eidB  = (int*)(ws + 37440032);             //    320,000
    _Float16*  WctAll= (_Float16*)(ws + 37760032);        //    524,288
    _Float16*  Wcte  = (_Float16*)(ws + 38284320);        //     32,768
    _Float16*  Wt1   = (_Float16*)(ws + 38317088);        //      8,192

    const int* srcB = eb;
    const int* dstB = eb + Eb;
    const int* srcR = er;

    // conversions (one kernel)
    conv_all_kernel<<<3604, 256, 0, stream>>>(
        Wf[0], Wsp[0], Wf[1], Wsp[1], Wf[2], Wsp[2], Wf[3], Wsp[3],
        We2, We1, x_prot, WctAll, Wcte, Wt1, xp16);

    // bond CSR build + radius CSR offsets
    hipMemsetAsync(cntI, 0, 160000, stream);  // cntI + curB contiguous
    count_int_kernel<<<(Eb + 255) / 256, 256, 0, stream>>>(dstB, Eb, cntI);
    scan_kernel<<<1, 1024, 0, stream>>>(cntI, offB);
    scatter_kernel<<<(Eb + 255) / 256, 256, 0, stream>>>(srcB, dstB, Eb, offB, curB, eidB);
    csr_off_kernel<<<(NN + 256) / 256, 256, 0, stream>>>(er + Er, Er, NN + 1, offR);

    // encoder
    enc1_mfma_kernel<<<157, 256, 0, stream>>>(xp16, Wt1, be1, H);
    {
        dim3 g(157, 1);
        gemm_mfma_kernel<<<g, 256, 0, stream>>>(H, Wcte, be2, be2, nullptr,
                                                xbuf, xhf, NN, 1);
    }

    // 4 CGConv layers (0-1: bond CSR, 2-3: radius CSR)
    for (int L = 0; L < 4; ++L) {
        dim3 g(157, 4);
        gemm_mfma_kernel<<<g, 256, 0, stream>>>(xhf, WctAll + L * 65536, bf[L],
                                                bsp[L], H, nullptr, nullptr, NN, 0);
        const int* sArr = (L < 2) ? eidB : srcR;
        const int* oArr = (L < 2) ? offB : offR;
        float* xout = (L == 3) ? (float*)d_out : xbuf;
        node_agg_kernel<<<NN / 4, 256, 0, stream>>>(H, sArr, oArr, xbuf, xout,
                                                    xhf, (L == 3) ? 0 : 1);
    }
    (void)n_in; (void)out_size; (void)ws_size;
}